// Round 2
// baseline (2260.279 us; speedup 1.0000x reference)
//
#include <hip/hip_runtime.h>
#include <math.h>

#define L_SEQ 2048
#define B_SZ 16
#define DIN 64
#define H_SZ 512
#define N_ST 64
#define N_LAYERS 4
#define BHSTRIDE (B_SZ * H_SZ)   // 8192

// ---------- cross-lane helpers ----------
__device__ __forceinline__ float rdlane(float v, int l) {
    return __builtin_bit_cast(float, __builtin_amdgcn_readlane(__builtin_bit_cast(int, v), l));
}

template <int CTRL>
__device__ __forceinline__ float dpp_add(float x) {
    // update_dpp(old=0, src=x, ctrl, row_mask=0xF, bank_mask=0xF, bound_ctrl=false):
    // lanes whose DPP source is invalid receive old (=0), so a plain add is safe.
    int s = __builtin_amdgcn_update_dpp(0, __builtin_bit_cast(int, x), CTRL, 0xF, 0xF, false);
    return x + __builtin_bit_cast(float, s);
}

// full-wave (64 lane) sum; result valid in lane 63. All adds on the VALU pipe (DPP),
// deliberately avoiding ds_swizzle (LDS pipe) which would bottleneck at 32 waves/CU.
__device__ __forceinline__ float wave_sum_lane63(float x) {
    x = dpp_add<0x111>(x);  // row_shr:1
    x = dpp_add<0x112>(x);  // row_shr:2
    x = dpp_add<0x114>(x);  // row_shr:4
    x = dpp_add<0x118>(x);  // row_shr:8  -> lane 15 of each row holds row sum
    x = dpp_add<0x142>(x);  // row_bcast:15 -> lane 31 = rows0+1, lane 63 = rows2+3
    x = dpp_add<0x143>(x);  // row_bcast:31 -> lane 63 = total
    return x;
}

// ---------- encoder: out[L*B, H] = x[L*B, DIN] @ W[DIN, H] + b ----------
// block = 256 threads (4 waves). Block computes 16 rows x 512 cols.
// wave w handles rows r0+4w .. r0+4w+3; each thread: 4 rows x 8 cols (stride 64).
__global__ __launch_bounds__(256, 4)
void encoder_kernel(const float* __restrict__ x, const float* __restrict__ W,
                    const float* __restrict__ bias, float* __restrict__ out)
{
    __shared__ float x_sh[16][DIN];
    const int tid  = threadIdx.x;
    const int lane = tid & 63;
    const int wave = tid >> 6;
    const int r0   = blockIdx.x * 16;

#pragma unroll
    for (int m = 0; m < 4; ++m) {
        int idx = tid + m * 256;
        int r = idx >> 6, k = idx & 63;
        x_sh[r][k] = x[(r0 + r) * DIN + k];
    }
    __syncthreads();

    float acc[4][8];
#pragma unroll
    for (int j = 0; j < 8; ++j) {
        float bv = bias[lane + 64 * j];
#pragma unroll
        for (int rr = 0; rr < 4; ++rr) acc[rr][j] = bv;
    }

    for (int k = 0; k < DIN; ++k) {
        float wv[8];
#pragma unroll
        for (int j = 0; j < 8; ++j) wv[j] = W[k * H_SZ + lane + 64 * j];
#pragma unroll
        for (int rr = 0; rr < 4; ++rr) {
            float xv = x_sh[wave * 4 + rr][k];   // wave-uniform LDS broadcast
#pragma unroll
            for (int j = 0; j < 8; ++j) acc[rr][j] = fmaf(xv, wv[j], acc[rr][j]);
        }
    }

#pragma unroll
    for (int rr = 0; rr < 4; ++rr)
#pragma unroll
        for (int j = 0; j < 8; ++j)
            out[(size_t)(r0 + wave * 4 + rr) * H_SZ + lane + 64 * j] = acc[rr][j];
}

// ---------- S4D scan layer ----------
// One wave per (b,h); lane = state index n. u,y layout [L,B,H].
// grid = 2048 blocks x 256 threads; block -> (b, h0..h0+3).
__global__ __launch_bounds__(256, 8)
void s4d_scan_kernel(const float* __restrict__ u, float* __restrict__ y,
                     const float* __restrict__ log_dt, const float* __restrict__ log_A_re,
                     const float* __restrict__ A_im, const float* __restrict__ C_re,
                     const float* __restrict__ C_im, const float* __restrict__ Dskip,
                     float* __restrict__ st_re, float* __restrict__ st_im, int layer)
{
    const int tid  = threadIdx.x;
    const int wave = tid >> 6;
    const int lane = tid & 63;
    const int b = blockIdx.x >> 7;                       // 128 blocks per batch
    const int h = ((blockIdx.x & 127) << 2) | wave;

    const int ph = layer * H_SZ + h;                     // [NL,H] params
    const int pn = ph * N_ST + lane;                     // [NL,H,N] params

    // ZOH discretization (computed once per lane; full-precision libm variants)
    float dt   = expf(log_dt[ph]);
    float Are  = -expf(log_A_re[pn]);
    float Aim  = A_im[pn];
    float mag  = expf(dt * Are);
    float phs  = dt * Aim;
    float dAr  = mag * cosf(phs);
    float dAi  = mag * sinf(phs);
    float invd = 1.0f / (Are * Are + Aim * Aim);
    float nr   = dAr - 1.0f;
    float dBr  = (nr * Are + dAi * Aim) * invd;          // (dA-1)/A
    float dBi  = (dAi * Are - nr * Aim) * invd;
    float Cr   = C_re[pn];
    float Ci   = C_im[pn];
    float Dv   = Dskip[ph];

    const float* ub = u + b * H_SZ + h;                  // element (t) at ub[t*BHSTRIDE]
    float*       yb = y + b * H_SZ + h;

    float sr = 0.f, si = 0.f;
    float unext = ub[(size_t)lane * BHSTRIDE];           // prefetch chunk 0

    for (int t0 = 0; t0 < L_SEQ; t0 += 64) {
        float ucur = unext;
        if (t0 + 64 < L_SEQ)
            unext = ub[(size_t)(t0 + 64 + lane) * BHSTRIDE];
        float yacc = 0.f;
#pragma unroll
        for (int i = 0; i < 64; ++i) {
            float ut = rdlane(ucur, i);                  // wave-uniform broadcast
            // s = dA*s + dB*u   (complex, u real)
            float nsr = fmaf(dAr, sr, fmaf(-dAi, si, dBr * ut));
            float nsi = fmaf(dAi, sr, fmaf(dAr, si, dBi * ut));
            sr = nsr; si = nsi;
            // per-lane contribution to Re(C . s)
            float c = fmaf(Cr, sr, -(Ci * si));
            float tot = wave_sum_lane63(c);
            float yv = fmaf(2.0f, rdlane(tot, 63), Dv * ut);
            yacc = (lane == i) ? yv : yacc;              // park y_{t0+i} in lane i
        }
        yb[(size_t)(t0 + lane) * BHSTRIDE] = yacc;       // one scatter store / 64 steps
    }

    // final state -> [NL,B,H,N]
    const size_t so = (((size_t)layer * B_SZ + b) * H_SZ + h) * N_ST + lane;
    st_re[so] = sr;
    st_im[so] = si;
}

extern "C" void kernel_launch(void* const* d_in, const int* in_sizes, int n_in,
                              void* d_out, int out_size, void* d_ws, size_t ws_size,
                              hipStream_t stream)
{
    const float* x        = (const float*)d_in[0];
    const float* enc_W    = (const float*)d_in[1];
    const float* enc_b    = (const float*)d_in[2];
    const float* log_dt   = (const float*)d_in[3];
    const float* log_A_re = (const float*)d_in[4];
    const float* A_im     = (const float*)d_in[5];
    const float* C_re     = (const float*)d_in[6];
    const float* C_im     = (const float*)d_in[7];
    const float* Dskip    = (const float*)d_in[8];

    float* out_h = (float*)d_out;                                  // [L,B,H]
    float* st_re = out_h + (size_t)L_SEQ * B_SZ * H_SZ;            // [NL,B,H,N]
    float* st_im = st_re + (size_t)N_LAYERS * B_SZ * H_SZ * N_ST;  // [NL,B,H,N]
    float* ws_h  = (float*)d_ws;                                   // [L,B,H] ping-pong

    encoder_kernel<<<2048, 256, 0, stream>>>(x, enc_W, enc_b, out_h);

    // layer ping-pong: out->ws->out->ws->out  (final h lands in d_out)
    s4d_scan_kernel<<<2048, 256, 0, stream>>>(out_h, ws_h, log_dt, log_A_re, A_im,
                                              C_re, C_im, Dskip, st_re, st_im, 0);
    s4d_scan_kernel<<<2048, 256, 0, stream>>>(ws_h, out_h, log_dt, log_A_re, A_im,
                                              C_re, C_im, Dskip, st_re, st_im, 1);
    s4d_scan_kernel<<<2048, 256, 0, stream>>>(out_h, ws_h, log_dt, log_A_re, A_im,
                                              C_re, C_im, Dskip, st_re, st_im, 2);
    s4d_scan_kernel<<<2048, 256, 0, stream>>>(ws_h, out_h, log_dt, log_A_re, A_im,
                                              C_re, C_im, Dskip, st_re, st_im, 3);
}

// Round 3
// 1178.914 us; speedup vs baseline: 1.9173x; 1.9173x over previous
//
#include <hip/hip_runtime.h>
#include <math.h>

#define L_SEQ 2048
#define B_SZ 16
#define DIN 64
#define H_SZ 512
#define N_ST 64
#define N_LAYERS 4
#define BHSTRIDE (B_SZ * H_SZ)   // 8192

__device__ __forceinline__ float rdlane(float v, int l) {
    return __builtin_bit_cast(float, __builtin_amdgcn_readlane(__builtin_bit_cast(int, v), l));
}

// ---------- encoder: out[L*B, H] = x[L*B, DIN] @ W[DIN, H] + b ----------
__global__ __launch_bounds__(256, 4)
void encoder_kernel(const float* __restrict__ x, const float* __restrict__ W,
                    const float* __restrict__ bias, float* __restrict__ out)
{
    __shared__ float x_sh[16][DIN];
    const int tid  = threadIdx.x;
    const int lane = tid & 63;
    const int wave = tid >> 6;
    const int r0   = blockIdx.x * 16;

#pragma unroll
    for (int m = 0; m < 4; ++m) {
        int idx = tid + m * 256;
        int r = idx >> 6, k = idx & 63;
        x_sh[r][k] = x[(r0 + r) * DIN + k];
    }
    __syncthreads();

    float acc[4][8];
#pragma unroll
    for (int j = 0; j < 8; ++j) {
        float bv = bias[lane + 64 * j];
#pragma unroll
        for (int rr = 0; rr < 4; ++rr) acc[rr][j] = bv;
    }

    for (int k = 0; k < DIN; ++k) {
        float wv[8];
#pragma unroll
        for (int j = 0; j < 8; ++j) wv[j] = W[k * H_SZ + lane + 64 * j];
#pragma unroll
        for (int rr = 0; rr < 4; ++rr) {
            float xv = x_sh[wave * 4 + rr][k];
#pragma unroll
            for (int j = 0; j < 8; ++j) acc[rr][j] = fmaf(xv, wv[j], acc[rr][j]);
        }
    }

#pragma unroll
    for (int rr = 0; rr < 4; ++rr)
#pragma unroll
        for (int j = 0; j < 8; ++j)
            out[(size_t)(r0 + wave * 4 + rr) * H_SZ + lane + 64 * j] = acc[rr][j];
}

// ---------- S4D scan layer ----------
// One wave per (b,h); lane = state index n. Per step: state update + per-lane
// contribution c written to LDS (1 ds_write_b32). Every 32 steps: transpose-read
// reduction (lane l sums column t=l&31 over 32 n's; odd stride 33 -> no bank
// conflicts; same-wave DS ordering -> NO barriers).
// u_lbh/y_lbh select [L,B,H] (stride BHSTRIDE) vs [B,H,L] (stride 1) layouts.
__global__ __launch_bounds__(256, 4)
void s4d_scan_kernel(const float* __restrict__ u, float* __restrict__ y,
                     const float* __restrict__ log_dt, const float* __restrict__ log_A_re,
                     const float* __restrict__ A_im, const float* __restrict__ C_re,
                     const float* __restrict__ C_im, const float* __restrict__ Dskip,
                     float* __restrict__ st_re, float* __restrict__ st_im,
                     int layer, int u_lbh, int y_lbh)
{
    __shared__ float c_sh[4 * 64 * 33];                  // 33792 B: per-wave 64(n) x 33(t-pad)

    const int tid  = threadIdx.x;
    const int wave = tid >> 6;
    const int lane = tid & 63;

    // XCD-aware swizzle: blocks covering h in [16k,16k+16) for one b share 64-B
    // lines of the [L,B,H] buffers; give them identical (blockIdx&7) -> same XCD.
    const int sub    = blockIdx.x >> 3;                  // 0..255
    const int b      = sub >> 4;                         // 0..15
    const int hgroup = ((blockIdx.x & 7) << 4) | (sub & 15);  // 0..127
    const int h      = (hgroup << 2) | wave;

    const int ph = layer * H_SZ + h;
    const int pn = ph * N_ST + lane;

    // ZOH discretization
    float dt   = expf(log_dt[ph]);
    float Are  = -expf(log_A_re[pn]);
    float Aim  = A_im[pn];
    float mag  = expf(dt * Are);
    float phs  = dt * Aim;
    float dAr  = mag * cosf(phs);
    float dAi  = mag * sinf(phs);
    float invd = 1.0f / (Are * Are + Aim * Aim);
    float nr   = dAr - 1.0f;
    float dBr  = (nr * Are + dAi * Aim) * invd;
    float dBi  = (dAi * Are - nr * Aim) * invd;
    float Cr2  = 2.0f * C_re[pn];
    float Ci2n = -2.0f * C_im[pn];
    float Dv   = Dskip[ph];

    const size_t u_stride = u_lbh ? (size_t)BHSTRIDE : 1;
    const size_t y_stride = y_lbh ? (size_t)BHSTRIDE : 1;
    const float* ub = u + (u_lbh ? (size_t)(b * H_SZ + h)
                                 : (size_t)(b * H_SZ + h) * L_SEQ);
    float*       yb = y + (y_lbh ? (size_t)(b * H_SZ + h)
                                 : (size_t)(b * H_SZ + h) * L_SEQ);

    // per-wave LDS bases (element indices)
    const int wbase   = wave * (64 * 33);
    const int wr_base = wbase + lane * 33;                       // (n=lane, t=i)
    const int rd_base = wbase + (lane >> 5) * (32 * 33) + (lane & 31);

    float sr = 0.f, si = 0.f;
    float unext = ub[(size_t)lane * u_stride];           // prefetch chunk 0

    for (int t0 = 0; t0 < L_SEQ; t0 += 64) {
        float ucur = unext;
        if (t0 + 64 < L_SEQ)
            unext = ub[(size_t)(t0 + 64 + lane) * u_stride];

#pragma unroll
        for (int half = 0; half < 2; ++half) {
#pragma unroll
            for (int i = 0; i < 32; ++i) {
                float ut = rdlane(ucur, half * 32 + i);
                float nsr = fmaf(dAr, sr, fmaf(-dAi, si, dBr * ut));
                float nsi = fmaf(dAi, sr, fmaf(dAr, si, dBi * ut));
                sr = nsr; si = nsi;
                c_sh[wr_base + i] = fmaf(Cr2, sr, Ci2n * si);
            }
            // reduce 64 columns: lane l sums t=l&31 over n-half (l>>5)
            float acc = 0.f;
#pragma unroll
            for (int n = 0; n < 32; ++n)
                acc += c_sh[rd_base + n * 33];
            acc += __shfl_xor(acc, 32, 64);              // merge n-halves
            float ul = half ? __shfl_xor(ucur, 32, 64) : ucur;
            float yv = fmaf(Dv, ul, acc);
            if (lane < 32)
                yb[(size_t)(t0 + half * 32 + lane) * y_stride] = yv;
        }
    }

    const size_t so = (((size_t)layer * B_SZ + b) * H_SZ + h) * N_ST + lane;
    st_re[so] = sr;
    st_im[so] = si;
}

extern "C" void kernel_launch(void* const* d_in, const int* in_sizes, int n_in,
                              void* d_out, int out_size, void* d_ws, size_t ws_size,
                              hipStream_t stream)
{
    const float* x        = (const float*)d_in[0];
    const float* enc_W    = (const float*)d_in[1];
    const float* enc_b    = (const float*)d_in[2];
    const float* log_dt   = (const float*)d_in[3];
    const float* log_A_re = (const float*)d_in[4];
    const float* A_im     = (const float*)d_in[5];
    const float* C_re     = (const float*)d_in[6];
    const float* C_im     = (const float*)d_in[7];
    const float* Dskip    = (const float*)d_in[8];

    float* out_h = (float*)d_out;                                  // [L,B,H] final
    float* st_re = out_h + (size_t)L_SEQ * B_SZ * H_SZ;            // [NL,B,H,N]
    float* st_im = st_re + (size_t)N_LAYERS * B_SZ * H_SZ * N_ST;
    float* ws_h  = (float*)d_ws;                                   // [B,H,L] scratch

    encoder_kernel<<<2048, 256, 0, stream>>>(x, enc_W, enc_b, out_h);

    // L1: out_h [L,B,H] -> ws [B,H,L]
    s4d_scan_kernel<<<2048, 256, 0, stream>>>(out_h, ws_h, log_dt, log_A_re, A_im,
                                              C_re, C_im, Dskip, st_re, st_im, 0, 1, 0);
    // L2: ws [B,H,L] -> out_h region reused as [B,H,L] scratch
    s4d_scan_kernel<<<2048, 256, 0, stream>>>(ws_h, out_h, log_dt, log_A_re, A_im,
                                              C_re, C_im, Dskip, st_re, st_im, 1, 0, 0);
    // L3: out_h [B,H,L] -> ws [B,H,L]
    s4d_scan_kernel<<<2048, 256, 0, stream>>>(out_h, ws_h, log_dt, log_A_re, A_im,
                                              C_re, C_im, Dskip, st_re, st_im, 2, 0, 0);
    // L4: ws [B,H,L] -> out_h [L,B,H] (final layout)
    s4d_scan_kernel<<<2048, 256, 0, stream>>>(ws_h, out_h, log_dt, log_A_re, A_im,
                                              C_re, C_im, Dskip, st_re, st_im, 3, 0, 1);
}

// Round 4
// 443.108 us; speedup vs baseline: 5.1010x; 2.6606x over previous
//
#include <hip/hip_runtime.h>
#include <math.h>

#define L_SEQ 2048
#define B_SZ 16
#define DIN 64
#define H_SZ 512
#define N_ST 64
#define N_LAYERS 4
#define Q_CHUNK 64
#define N_CHUNKS (L_SEQ / Q_CHUNK)   // 32

typedef _Float16 f16;
typedef _Float16 f16x8 __attribute__((ext_vector_type(8)));
typedef float    f32x4 __attribute__((ext_vector_type(4)));

// ---------- cross-lane helpers ----------
template <int CTRL>
__device__ __forceinline__ float dpp_add(float x) {
    int s = __builtin_amdgcn_update_dpp(0, __builtin_bit_cast(int, x), CTRL, 0xF, 0xF, false);
    return x + __builtin_bit_cast(float, s);
}
// 64-lane sum, valid in lane 63 (all on VALU pipe)
__device__ __forceinline__ float wave_sum_lane63(float x) {
    x = dpp_add<0x111>(x);  // row_shr:1
    x = dpp_add<0x112>(x);  // row_shr:2
    x = dpp_add<0x114>(x);  // row_shr:4
    x = dpp_add<0x118>(x);  // row_shr:8
    x = dpp_add<0x142>(x);  // row_bcast:15
    x = dpp_add<0x143>(x);  // row_bcast:31
    return x;
}

// ---------- encoder: out[h][b][l] = sum_k x[l][b][k] W[k][h] + bias[h] ----------
// grid: 8 h-tiles x 32 l-tiles x 16 b = 4096 blocks x 256 threads
__global__ __launch_bounds__(256, 4)
void encoder_hbl_kernel(const float* __restrict__ x, const float* __restrict__ W,
                        const float* __restrict__ bias, float* __restrict__ out)
{
    __shared__ float x_sh[64][65];   // [l][k]
    __shared__ float w_sh[64][65];   // [k][h]
    __shared__ float b_sh[64];
    const int tid = threadIdx.x;
    const int bid = blockIdx.x;
    const int bb  = bid & 15;
    const int lt  = (bid >> 4) & 31;
    const int ht  = bid >> 9;          // 0..7
    const int l0 = lt * 64, h0 = ht * 64;

#pragma unroll
    for (int i = 0; i < 16; ++i) {
        int idx = tid + i * 256;       // 0..4095
        int r = idx >> 6, k = idx & 63;
        x_sh[r][k] = x[((size_t)(l0 + r) * B_SZ + bb) * DIN + k];
        w_sh[r][k] = W[(size_t)r * H_SZ + h0 + k];   // w_sh[k_row=r][h_col=k]
    }
    if (tid < 64) b_sh[tid] = bias[h0 + tid];
    __syncthreads();

    const int th = tid >> 4;           // 0..15 -> h-quad
    const int tl = tid & 15;           // 0..15 -> l-quad
    float acc[4][4];
#pragma unroll
    for (int i = 0; i < 4; ++i)
#pragma unroll
        for (int j = 0; j < 4; ++j) acc[i][j] = b_sh[th * 4 + i];

    for (int k = 0; k < DIN; ++k) {
        float wv[4], xv[4];
#pragma unroll
        for (int i = 0; i < 4; ++i) wv[i] = w_sh[k][th * 4 + i];
#pragma unroll
        for (int j = 0; j < 4; ++j) xv[j] = x_sh[tl * 4 + j][k];
#pragma unroll
        for (int i = 0; i < 4; ++i)
#pragma unroll
            for (int j = 0; j < 4; ++j) acc[i][j] = fmaf(wv[i], xv[j], acc[i][j]);
    }

#pragma unroll
    for (int i = 0; i < 4; ++i) {
        float4 v = make_float4(acc[i][0], acc[i][1], acc[i][2], acc[i][3]);
        *(float4*)&out[((size_t)(h0 + th * 4 + i) * B_SZ + bb) * L_SEQ + l0 + tl * 4] = v;
    }
}

// ---------- S4D layer: chunked conv + state correction, one block per h ----------
__global__ __launch_bounds__(1024, 8)
void s4d_layer_kernel(const float* __restrict__ u_in,   // [H][B][L]
                      float* __restrict__ y_out,        // [H][B][L]
                      const float* __restrict__ log_dt, const float* __restrict__ log_A_re,
                      const float* __restrict__ A_im, const float* __restrict__ C_re,
                      const float* __restrict__ C_im, const float* __restrict__ Dskip,
                      float* __restrict__ st_re, float* __restrict__ st_im, int layer)
{
    __shared__ f16   A_lds[192][72];    // rows 0..63: Toeplitz(K); 64..127: E_re; 128..191: E_im
    __shared__ f16   G_lds[64][136];    // G[t][n2], n2-contiguous
    __shared__ f16   U_sh[16][72];      // U^T fp16: [b][t']
    __shared__ float u_sh[16][65];      // fp32 u for D-skip
    __shared__ f16   s_frag[16][136];   // S^T fp16: [b][n2]
    __shared__ float z_sh[128][17];
    __shared__ float s_sh[128][17];
    __shared__ float yp_sh[64][17];
    __shared__ float K_sh[64];
    __shared__ float w_sh[64][2];

    const int tid  = threadIdx.x;
    const int wave = tid >> 6;
    const int lane = tid & 63;
    const int h    = blockIdx.x;

    const int ph = layer * H_SZ + h;
    const int pn = ph * N_ST + lane;

    // ---- inline per-h table build ----
    {
        float dt   = expf(log_dt[ph]);
        float Are  = -expf(log_A_re[pn]);
        float Aim  = A_im[pn];
        float mg   = expf(dt * Are);
        float phs  = dt * Aim;
        float dAr  = mg * cosf(phs);
        float dAi  = mg * sinf(phs);
        float invd = 1.0f / (Are * Are + Aim * Aim);
        float nr   = dAr - 1.0f;
        float dBr  = (nr * Are + dAi * Aim) * invd;
        float dBi  = (dAi * Are - nr * Aim) * invd;
        float Cr   = C_re[pn];
        float Ci   = C_im[pn];
        float CBr  = Cr * dBr - Ci * dBi;   // C*dB
        float CBi  = Cr * dBi + Ci * dBr;

        float Pr = 1.f, Pi = 0.f;           // P = dA^j
        for (int j = 0; j <= 64; ++j) {
            if (j <= 63) {
                if (wave == 2) {
                    float ks = wave_sum_lane63(2.f * (Pr * CBr - Pi * CBi));
                    if (lane == 63) K_sh[j] = ks;
                }
                if (wave == 0) {            // E[n][m=63-j] = dA^j * dB
                    A_lds[64 + lane][63 - j]  = (f16)(Pr * dBr - Pi * dBi);
                    A_lds[128 + lane][63 - j] = (f16)(Pr * dBi + Pi * dBr);
                }
            }
            if (j >= 1 && wave == 1) {      // G[t=j-1]: 2Re(C dA^{t+1}), -2Im(...)
                G_lds[j - 1][lane]      = (f16)( 2.f * (Cr * Pr - Ci * Pi));
                G_lds[j - 1][64 + lane] = (f16)(-2.f * (Cr * Pi + Ci * Pr));
            }
            if (j == 64 && wave == 3) { w_sh[lane][0] = Pr; w_sh[lane][1] = Pi; }
            float nPr = Pr * dAr - Pi * dAi;
            float nPi = Pr * dAi + Pi * dAr;
            Pr = nPr; Pi = nPi;
        }
    }
    __syncthreads();
    // Toeplitz expansion + state zero-init
#pragma unroll
    for (int e = tid; e < 64 * 64; e += 1024) {
        int i = e >> 6, j = e & 63;
        A_lds[i][j] = (j <= i) ? (f16)K_sh[i - j] : (f16)0.f;
    }
    for (int e = tid; e < 128 * 17; e += 1024) (&s_sh[0][0])[e] = 0.f;
    for (int e = tid; e < 16 * 136; e += 1024) (&s_frag[0][0])[e] = (f16)0.f;

    const float Dv = Dskip[ph];
    const float* ub = u_in + (size_t)h * B_SZ * L_SEQ;
    float*       yb = y_out + (size_t)h * B_SZ * L_SEQ;

    const int frow = lane & 15;
    const int fk   = (lane >> 4) * 8;
    const int stb  = tid >> 6;          // staging: b
    const int sun  = tid >> 4;          // state:   n  (0..63)
    const int sub  = tid & 15;          // state:   b

    for (int c = 0; c < N_CHUNKS; ++c) {
        __syncthreads();                // protect U_sh/u_sh/s_frag from prev readers
        {
            float v = ub[(size_t)stb * L_SEQ + c * 64 + lane];
            U_sh[stb][lane] = (f16)v;
            u_sh[stb][lane] = v;
        }
        __syncthreads();

        f32x4 acc = {0.f, 0.f, 0.f, 0.f};
        if (wave < 12) {                // [T;E](192x64) . U(64x16), M-tile = wave
            const int m0 = wave * 16;
#pragma unroll
            for (int ks = 0; ks < 2; ++ks) {
                f16x8 av = *(const f16x8*)&A_lds[m0 + frow][fk + 32 * ks];
                f16x8 bv = *(const f16x8*)&U_sh[frow][fk + 32 * ks];
                acc = __builtin_amdgcn_mfma_f32_16x16x32_f16(av, bv, acc, 0, 0, 0);
            }
        } else {                        // G(64x128) . S(128x16), M-tile = wave-12
            const int m0 = (wave - 12) * 16;
#pragma unroll
            for (int ks = 0; ks < 4; ++ks) {
                f16x8 av = *(const f16x8*)&G_lds[m0 + frow][fk + 32 * ks];
                f16x8 bv = *(const f16x8*)&s_frag[frow][fk + 32 * ks];
                acc = __builtin_amdgcn_mfma_f32_16x16x32_f16(av, bv, acc, 0, 0, 0);
            }
        }
        if (wave >= 4 && wave < 12) {   // z rows
            const int n2b = wave * 16 - 64;
#pragma unroll
            for (int r = 0; r < 4; ++r)
                z_sh[n2b + (lane >> 4) * 4 + r][frow] = acc[r];
        } else if (wave >= 12) {        // state-correction partial
            const int m0 = (wave - 12) * 16;
#pragma unroll
            for (int r = 0; r < 4; ++r)
                yp_sh[m0 + (lane >> 4) * 4 + r][frow] = acc[r];
        }
        __syncthreads();

        if (wave < 4) {                 // y = conv + corr + D*u  -> global
            const int m0 = wave * 16;
            const int t0c = m0 + (lane >> 4) * 4;
            float yv[4];
#pragma unroll
            for (int r = 0; r < 4; ++r) {
                int t = t0c + r;
                yv[r] = acc[r] + yp_sh[t][frow] + Dv * u_sh[frow][t];
            }
            *(float4*)&yb[(size_t)frow * L_SEQ + c * 64 + t0c] =
                make_float4(yv[0], yv[1], yv[2], yv[3]);
        }
        {                               // state update: s = w*s + z  (thread <-> (n,b))
            float sre = s_sh[sun][sub],      sim = s_sh[64 + sun][sub];
            float zre = z_sh[sun][sub],      zim = z_sh[64 + sun][sub];
            float wr  = w_sh[sun][0],        wi  = w_sh[sun][1];
            float nre = wr * sre - wi * sim + zre;
            float nim = wi * sre + wr * sim + zim;
            s_sh[sun][sub] = nre;  s_sh[64 + sun][sub] = nim;
            s_frag[sub][sun] = (f16)nre;  s_frag[sub][64 + sun] = (f16)nim;
        }
    }
    __syncthreads();
    // final states -> [NL,B,H,N]; coalesced over n
    {
        int n = tid & 63, b = tid >> 6;
        size_t so = (((size_t)layer * B_SZ + b) * H_SZ + h) * N_ST + n;
        st_re[so] = s_sh[n][b];
        st_im[so] = s_sh[64 + n][b];
    }
}

// ---------- [H][B][L] -> [L][B][H] transpose ----------
__global__ __launch_bounds__(256, 4)
void hbl_to_lbh_kernel(const float* __restrict__ in, float* __restrict__ out)
{
    __shared__ float t_sh[64][65];
    const int tid = threadIdx.x, bid = blockIdx.x;
    const int bb = bid & 15, lt = (bid >> 4) & 31, ht = bid >> 9;
    const int l0 = lt * 64, h0 = ht * 64;
#pragma unroll
    for (int i = 0; i < 16; ++i) {
        int idx = tid + i * 256;
        int hh = idx >> 6, ll = idx & 63;
        t_sh[hh][ll] = in[((size_t)(h0 + hh) * B_SZ + bb) * L_SEQ + l0 + ll];
    }
    __syncthreads();
#pragma unroll
    for (int i = 0; i < 16; ++i) {
        int idx = tid + i * 256;
        int ll = idx >> 6, hh = idx & 63;
        out[((size_t)(l0 + ll) * B_SZ + bb) * H_SZ + h0 + hh] = t_sh[hh][ll];
    }
}

extern "C" void kernel_launch(void* const* d_in, const int* in_sizes, int n_in,
                              void* d_out, int out_size, void* d_ws, size_t ws_size,
                              hipStream_t stream)
{
    const float* x        = (const float*)d_in[0];
    const float* enc_W    = (const float*)d_in[1];
    const float* enc_b    = (const float*)d_in[2];
    const float* log_dt   = (const float*)d_in[3];
    const float* log_A_re = (const float*)d_in[4];
    const float* A_im     = (const float*)d_in[5];
    const float* C_re     = (const float*)d_in[6];
    const float* C_im     = (const float*)d_in[7];
    const float* Dskip    = (const float*)d_in[8];

    float* out_lbh = (float*)d_out;                                  // [L,B,H]
    float* st_re   = out_lbh + (size_t)L_SEQ * B_SZ * H_SZ;
    float* st_im   = st_re + (size_t)N_LAYERS * B_SZ * H_SZ * N_ST;
    float* B0 = (float*)d_ws;        // [H][B][L] scratch (64 MB)
    float* B1 = out_lbh;             // reuse d_out y-region as [H][B][L] scratch

    encoder_hbl_kernel<<<4096, 256, 0, stream>>>(x, enc_W, enc_b, B0);

    s4d_layer_kernel<<<512, 1024, 0, stream>>>(B0, B1, log_dt, log_A_re, A_im,
                                               C_re, C_im, Dskip, st_re, st_im, 0);
    s4d_layer_kernel<<<512, 1024, 0, stream>>>(B1, B0, log_dt, log_A_re, A_im,
                                               C_re, C_im, Dskip, st_re, st_im, 1);
    s4d_layer_kernel<<<512, 1024, 0, stream>>>(B0, B1, log_dt, log_A_re, A_im,
                                               C_re, C_im, Dskip, st_re, st_im, 2);
    s4d_layer_kernel<<<512, 1024, 0, stream>>>(B1, B0, log_dt, log_A_re, A_im,
                                               C_re, C_im, Dskip, st_re, st_im, 3);

    hbl_to_lbh_kernel<<<4096, 256, 0, stream>>>(B0, out_lbh);        // final y -> [L,B,H]
}

// Round 5
// 351.328 us; speedup vs baseline: 6.4335x; 1.2612x over previous
//
#include <hip/hip_runtime.h>
#include <math.h>

#define L_SEQ 2048
#define B_SZ 16
#define DIN 64
#define H_SZ 512
#define N_ST 64
#define N_LAYERS 4
#define Q_CHUNK 64
#define N_CHUNKS (L_SEQ / Q_CHUNK)   // 32

typedef _Float16 f16;
typedef _Float16 f16x8 __attribute__((ext_vector_type(8)));
typedef _Float16 f16x4 __attribute__((ext_vector_type(4)));
typedef _Float16 f16x2 __attribute__((ext_vector_type(2)));
typedef float    f32x4 __attribute__((ext_vector_type(4)));
typedef float    f32x2 __attribute__((ext_vector_type(2)));

// ---------- cross-lane helpers ----------
template <int CTRL>
__device__ __forceinline__ float dpp_add(float x) {
    int s = __builtin_amdgcn_update_dpp(0, __builtin_bit_cast(int, x), CTRL, 0xF, 0xF, false);
    return x + __builtin_bit_cast(float, s);
}
// 64-lane sum, valid in lane 63 (all on VALU pipe)
__device__ __forceinline__ float wave_sum_lane63(float x) {
    x = dpp_add<0x111>(x);
    x = dpp_add<0x112>(x);
    x = dpp_add<0x114>(x);
    x = dpp_add<0x118>(x);
    x = dpp_add<0x142>(x);
    x = dpp_add<0x143>(x);
    return x;
}

// ---------- encoder: out[h][b][l] = sum_k x[l][b][k] W[k][h] + bias[h] ----------
__global__ __launch_bounds__(256, 4)
void encoder_hbl_kernel(const float* __restrict__ x, const float* __restrict__ W,
                        const float* __restrict__ bias, float* __restrict__ out)
{
    __shared__ float x_sh[64][65];   // [l][k]
    __shared__ float w_sh[64][65];   // [k][h]
    __shared__ float b_sh[64];
    const int tid = threadIdx.x;
    const int bid = blockIdx.x;
    const int bb  = bid & 15;
    const int lt  = (bid >> 4) & 31;
    const int ht  = bid >> 9;
    const int l0 = lt * 64, h0 = ht * 64;

#pragma unroll
    for (int i = 0; i < 16; ++i) {
        int idx = tid + i * 256;
        int r = idx >> 6, k = idx & 63;
        x_sh[r][k] = x[((size_t)(l0 + r) * B_SZ + bb) * DIN + k];
        w_sh[r][k] = W[(size_t)r * H_SZ + h0 + k];
    }
    if (tid < 64) b_sh[tid] = bias[h0 + tid];
    __syncthreads();

    const int th = tid >> 4;
    const int tl = tid & 15;
    float acc[4][4];
#pragma unroll
    for (int i = 0; i < 4; ++i)
#pragma unroll
        for (int j = 0; j < 4; ++j) acc[i][j] = b_sh[th * 4 + i];

    for (int k = 0; k < DIN; ++k) {
        float wv[4], xv[4];
#pragma unroll
        for (int i = 0; i < 4; ++i) wv[i] = w_sh[k][th * 4 + i];
#pragma unroll
        for (int j = 0; j < 4; ++j) xv[j] = x_sh[tl * 4 + j][k];
#pragma unroll
        for (int i = 0; i < 4; ++i)
#pragma unroll
            for (int j = 0; j < 4; ++j) acc[i][j] = fmaf(wv[i], xv[j], acc[i][j]);
    }

#pragma unroll
    for (int i = 0; i < 4; ++i) {
        float4 v = make_float4(acc[i][0], acc[i][1], acc[i][2], acc[i][3]);
        *(float4*)&out[((size_t)(h0 + th * 4 + i) * B_SZ + bb) * L_SEQ + l0 + tl * 4] = v;
    }
}

// ---------- S4D layer: chunked conv + state correction, one block per h ----------
// Layouts (all conflict-free for the b128 access pattern):
//   A_lds rows 0..63  : Toeplitz(K)[t][t']          (M = t)
//   A_lds rows 64..191: E interleaved [2n+p][m]     (M = n2, p=0 Re / p=1 Im)
//   G_lds [t][n2]     : n2 = 2n (+2Re(C dA^{t+1})), 2n+1 (-2Im)
//   U_sh  [buf][b][t] f16 ; s_frag [buf][b][n2] f16 (interleaved)
//   z_sh  [b][n2] f32 ; yp_sh [b][t] f32
// State (fp32) lives in registers: thread (b=wave, n=lane).
__global__ __launch_bounds__(1024, 8)
void s4d_layer_kernel(const float* __restrict__ u_in,   // [H][B][L]
                      float* __restrict__ y_out,        // [H][B][L]
                      const float* __restrict__ log_dt, const float* __restrict__ log_A_re,
                      const float* __restrict__ A_im, const float* __restrict__ C_re,
                      const float* __restrict__ C_im, const float* __restrict__ Dskip,
                      float* __restrict__ st_re, float* __restrict__ st_im, int layer)
{
    __shared__ f16   A_lds[192][72];      // 27648 B
    __shared__ f16   G_lds[64][136];      // 17408 B
    __shared__ f16   U_sh[2][16][72];     //  4608 B
    __shared__ f16   s_frag[2][16][136];  //  8704 B
    __shared__ float z_sh[16][136];       //  8704 B
    __shared__ float yp_sh[16][72];       //  4608 B
    __shared__ float K_sh[64];            //   256 B   -> 71936 B total, 2 blocks/CU

    const int tid  = threadIdx.x;
    const int wave = tid >> 6;
    const int lane = tid & 63;
    const int h    = blockIdx.x;

    const int ph = layer * H_SZ + h;
    const int pn = ph * N_ST + lane;

    float wr, wi;                          // dA^64 for n = lane (every thread)
    // ---- per-h table build (all waves run the power recurrence for n=lane) ----
    {
        float dt   = expf(log_dt[ph]);
        float Are  = -expf(log_A_re[pn]);
        float Aim  = A_im[pn];
        float mg   = expf(dt * Are);
        float phs  = dt * Aim;
        float dAr  = mg * cosf(phs);
        float dAi  = mg * sinf(phs);
        float invd = 1.0f / (Are * Are + Aim * Aim);
        float nr   = dAr - 1.0f;
        float dBr  = (nr * Are + dAi * Aim) * invd;
        float dBi  = (dAi * Are - nr * Aim) * invd;
        float Cr   = C_re[pn];
        float Ci   = C_im[pn];
        float CBr  = Cr * dBr - Ci * dBi;
        float CBi  = Cr * dBi + Ci * dBr;

        float Pr = 1.f, Pi = 0.f;          // P = dA^j
        for (int j = 0; j <= 64; ++j) {
            if (j <= 63) {
                if (wave == 2) {
                    float ks = wave_sum_lane63(2.f * (Pr * CBr - Pi * CBi));
                    if (lane == 63) K_sh[j] = ks;
                }
                if (wave == 0) {           // E rows interleaved: [2n]=Re, [2n+1]=Im
                    A_lds[64 + 2 * lane][63 - j]     = (f16)(Pr * dBr - Pi * dBi);
                    A_lds[64 + 2 * lane + 1][63 - j] = (f16)(Pr * dBi + Pi * dBr);
                }
            }
            if (j >= 1 && wave == 1) {     // G[t=j-1][n2]
                G_lds[j - 1][2 * lane]     = (f16)( 2.f * (Cr * Pr - Ci * Pi));
                G_lds[j - 1][2 * lane + 1] = (f16)(-2.f * (Cr * Pi + Ci * Pr));
            }
            if (j == 64) { wr = Pr; wi = Pi; }
            float nPr = Pr * dAr - Pi * dAi;
            float nPi = Pr * dAi + Pi * dAr;
            Pr = nPr; Pi = nPi;
        }
    }
    __syncthreads();
    // Toeplitz expansion + s_frag zero-init
#pragma unroll
    for (int e = tid; e < 64 * 64; e += 1024) {
        int i = e >> 6, j = e & 63;
        A_lds[i][j] = (j <= i) ? (f16)K_sh[i - j] : (f16)0.f;
    }
    for (int e = tid; e < 2 * 16 * 136 / 2; e += 1024)
        ((unsigned int*)s_frag)[e] = 0u;
    __syncthreads();

    // ---- preload chunk-invariant MFMA A-fragments into registers ----
    const int frow = lane & 15;
    const int fk   = (lane >> 4) * 8;
    f16x8 a_frag[4];
    if (wave < 12) {
        const int m0 = wave * 16;
#pragma unroll
        for (int ks = 0; ks < 2; ++ks)
            a_frag[ks] = *(const f16x8*)&A_lds[m0 + frow][fk + 32 * ks];
    } else {
        const int m0 = (wave - 12) * 16;
#pragma unroll
        for (int ks = 0; ks < 4; ++ks)
            a_frag[ks] = *(const f16x8*)&G_lds[m0 + frow][fk + 32 * ks];
    }

    const float Dv = Dskip[ph];
    const float* ub = u_in + (size_t)h * B_SZ * L_SEQ;
    float*       yb = y_out + (size_t)h * B_SZ * L_SEQ;

    float sr = 0.f, si = 0.f;              // state regs: (b=wave, n=lane)
    float v = ub[(size_t)wave * L_SEQ + lane];   // prefetched u chunk 0

    for (int c = 0; c < N_CHUNKS; ++c) {
        const int buf = c & 1;
        // stage current chunk (wave=b), issue prefetch for next chunk
        U_sh[buf][wave][lane] = (f16)v;
        float vn = 0.f;
        if (c + 1 < N_CHUNKS)
            vn = ub[(size_t)wave * L_SEQ + (c + 1) * 64 + lane];
        __syncthreads();                   // U_sh[buf], s_frag[buf] visible

        f32x4 acc = {0.f, 0.f, 0.f, 0.f};
        if (wave < 12) {                   // [T;E](192x64) . U(64x16)
#pragma unroll
            for (int ks = 0; ks < 2; ++ks) {
                f16x8 bv = *(const f16x8*)&U_sh[buf][frow][fk + 32 * ks];
                acc = __builtin_amdgcn_mfma_f32_16x16x32_f16(a_frag[ks], bv, acc, 0, 0, 0);
            }
        } else {                           // G(64x128) . S(128x16)
#pragma unroll
            for (int ks = 0; ks < 4; ++ks) {
                f16x8 bv = *(const f16x8*)&s_frag[buf][frow][fk + 32 * ks];
                acc = __builtin_amdgcn_mfma_f32_16x16x32_f16(a_frag[ks], bv, acc, 0, 0, 0);
            }
        }
        if (wave >= 4 && wave < 12) {      // z rows n2 (4 consecutive) at col b=frow
            *(f32x4*)&z_sh[frow][(wave * 16 - 64) + (lane >> 4) * 4] = acc;
        } else if (wave >= 12) {           // yp rows t at col b=frow
            *(f32x4*)&yp_sh[frow][(wave - 12) * 16 + (lane >> 4) * 4] = acc;
        }
        __syncthreads();                   // z, yp visible

        if (wave < 4) {                    // y = conv + corr + D*u -> global
            const int t0c = wave * 16 + (lane >> 4) * 4;
            f32x4 yp = *(const f32x4*)&yp_sh[frow][t0c];
            f16x4 uf = *(const f16x4*)&U_sh[buf][frow][t0c];
            float4 yv;
            yv.x = acc[0] + yp[0] + Dv * (float)uf[0];
            yv.y = acc[1] + yp[1] + Dv * (float)uf[1];
            yv.z = acc[2] + yp[2] + Dv * (float)uf[2];
            yv.w = acc[3] + yp[3] + Dv * (float)uf[3];
            *(float4*)&yb[(size_t)frow * L_SEQ + c * 64 + t0c] = yv;
        }
        {                                  // state update: s = w*s + z
            f32x2 z = *(const f32x2*)&z_sh[wave][2 * lane];
            float nre = wr * sr - wi * si + z[0];
            float nim = wi * sr + wr * si + z[1];
            sr = nre; si = nim;
            f16x2 sf; sf[0] = (f16)nre; sf[1] = (f16)nim;
            *(f16x2*)&s_frag[buf ^ 1][wave][2 * lane] = sf;
        }
        v = vn;
    }

    // final states -> [NL,B,H,N] straight from registers (coalesced over n)
    {
        const size_t so = (((size_t)layer * B_SZ + wave) * H_SZ + h) * N_ST + lane;
        st_re[so] = sr;
        st_im[so] = si;
    }
}

// ---------- [H][B][L] -> [L][B][H] transpose ----------
__global__ __launch_bounds__(256, 4)
void hbl_to_lbh_kernel(const float* __restrict__ in, float* __restrict__ out)
{
    __shared__ float t_sh[64][65];
    const int tid = threadIdx.x, bid = blockIdx.x;
    const int bb = bid & 15, lt = (bid >> 4) & 31, ht = bid >> 9;
    const int l0 = lt * 64, h0 = ht * 64;
#pragma unroll
    for (int i = 0; i < 16; ++i) {
        int idx = tid + i * 256;
        int hh = idx >> 6, ll = idx & 63;
        t_sh[hh][ll] = in[((size_t)(h0 + hh) * B_SZ + bb) * L_SEQ + l0 + ll];
    }
    __syncthreads();
#pragma unroll
    for (int i = 0; i < 16; ++i) {
        int idx = tid + i * 256;
        int ll = idx >> 6, hh = idx & 63;
        out[((size_t)(l0 + ll) * B_SZ + bb) * H_SZ + h0 + hh] = t_sh[hh][ll];
    }
}

extern "C" void kernel_launch(void* const* d_in, const int* in_sizes, int n_in,
                              void* d_out, int out_size, void* d_ws, size_t ws_size,
                              hipStream_t stream)
{
    const float* x        = (const float*)d_in[0];
    const float* enc_W    = (const float*)d_in[1];
    const float* enc_b    = (const float*)d_in[2];
    const float* log_dt   = (const float*)d_in[3];
    const float* log_A_re = (const float*)d_in[4];
    const float* A_im     = (const float*)d_in[5];
    const float* C_re     = (const float*)d_in[6];
    const float* C_im     = (const float*)d_in[7];
    const float* Dskip    = (const float*)d_in[8];

    float* out_lbh = (float*)d_out;                                  // [L,B,H]
    float* st_re   = out_lbh + (size_t)L_SEQ * B_SZ * H_SZ;
    float* st_im   = st_re + (size_t)N_LAYERS * B_SZ * H_SZ * N_ST;
    float* B0 = (float*)d_ws;        // [H][B][L] scratch (64 MB)
    float* B1 = out_lbh;             // reuse d_out y-region as [H][B][L] scratch

    encoder_hbl_kernel<<<4096, 256, 0, stream>>>(x, enc_W, enc_b, B0);

    s4d_layer_kernel<<<512, 1024, 0, stream>>>(B0, B1, log_dt, log_A_re, A_im,
                                               C_re, C_im, Dskip, st_re, st_im, 0);
    s4d_layer_kernel<<<512, 1024, 0, stream>>>(B1, B0, log_dt, log_A_re, A_im,
                                               C_re, C_im, Dskip, st_re, st_im, 1);
    s4d_layer_kernel<<<512, 1024, 0, stream>>>(B0, B1, log_dt, log_A_re, A_im,
                                               C_re, C_im, Dskip, st_re, st_im, 2);
    s4d_layer_kernel<<<512, 1024, 0, stream>>>(B1, B0, log_dt, log_A_re, A_im,
                                               C_re, C_im, Dskip, st_re, st_im, 3);

    hbl_to_lbh_kernel<<<4096, 256, 0, stream>>>(B0, out_lbh);        // final y -> [L,B,H]
}